// Round 7
// baseline (328.506 us; speedup 1.0000x reference)
//
#include <hip/hip_runtime.h>
#include <hip/hip_bf16.h>

typedef unsigned short ushortT;
typedef __bf16 bf16x8 __attribute__((ext_vector_type(8)));
typedef float f32x4 __attribute__((ext_vector_type(4)));

#define OUT_SCALE 0.001f

// fast GELU: v * sigmoid(1.5957691*(v + 0.044715 v^3)); |err vs exact| <~1e-3
__device__ __forceinline__ float gelu_fast(float v) {
    const float u = v * fmaf(0.044715f * v, v, 1.0f);
    const float e = __expf(-1.5957691216057308f * u);
    return v * __builtin_amdgcn_rcpf(1.0f + e);
}
__device__ __forceinline__ ushortT f2bf(float f) {
    __hip_bfloat16 h = __float2bfloat16(f);
    return *reinterpret_cast<ushortT*>(&h);
}

// ---------------------------------------------------------------------------
// K2: z path, split per 16 channels. grid (64,4), 256 thr, LDS 16.6 KB.
// gelu(z + dwconv3x3(z) + b) -> bf16 ZB[b][v][u][c64]
// ---------------------------------------------------------------------------
__global__ __launch_bounds__(256) void k_gelu_z(
    const float* __restrict__ z, const float* __restrict__ wz,
    const float* __restrict__ bz, ushortT* __restrict__ zbuf)
{
    const int b  = blockIdx.x;
    const int cg = blockIdx.y;        // channel group of 16
    const int tid = threadIdx.x;

    __shared__ float zs[16 * 260];    // 16 ch x 256 (+4 pad)

    for (int i = tid; i < 1024; i += 256) {
        const int c_l = i >> 6, pos = i & 63;
        *(float4*)(zs + c_l * 260 + pos * 4) =
            *(const float4*)(z + ((size_t)(b * 64 + cg * 16 + c_l)) * 256 + pos * 4);
    }
    __syncthreads();

    const int c_l = tid & 15;         // local channel
    const int v   = tid >> 4;         // search col (0..15)
    const int c   = cg * 16 + c_l;

    float w[9];
    #pragma unroll
    for (int i = 0; i < 9; ++i) w[i] = wz[c * 9 + i];
    const float bias = bz[c];
    const float* zc = zs + c_l * 260;
    ushortT* zo = zbuf + (size_t)b * 16384 + c;

    #pragma unroll
    for (int u = 0; u < 16; ++u) {
        float acc = bias;
        #pragma unroll
        for (int dr = 0; dr < 3; ++dr) {
            const int uu = u + dr - 1;
            if (uu < 0 || uu >= 16) continue;
            #pragma unroll
            for (int dc = 0; dc < 3; ++dc) {
                const int vv = v + dc - 1;
                if (vv < 0 || vv >= 16) continue;
                acc += zc[uu * 16 + vv] * w[dr * 3 + dc];
            }
        }
        const float y = acc + zc[u * 16 + v];
        zo[(v * 16 + u) * 64] = f2bf(gelu_fast(y));
    }
}

// ---------------------------------------------------------------------------
// K-fused (R=2): gelu-x + correlation, ONE barrier, no LDS accumulator.
// Phase A: R5's branchless clamped-load form (best measured).
// NEW: g=0 zbuf B-fragments loaded BEFORE the barrier (fly during the vmcnt
// drain); g=1 B-fragments issued at Phase-B entry (fly under g=0 ds/MFMA).
// Phase B: pure LDS ds_read + MFMA; f32x4 stores to part (disjoint).
// ---------------------------------------------------------------------------
__global__ __launch_bounds__(512, 4) void k_fused(
    const float* __restrict__ x, const float* __restrict__ wx,
    const float* __restrict__ bx, const ushortT* __restrict__ zbuf,
    float* __restrict__ part)
{
    // bijective XCD swizzle: 3072 = 8 * 384; XCD i gets b in [8i, 8i+8)
    const int lin = blockIdx.x;
    const int sw  = ((lin & 7) * 384) + (lin >> 3);
    const int k2  = sw % 48;
    const int b   = sw / 48;
    const int r0  = k2 * 2;
    const int tid = threadIdx.x;

    __shared__ ushortT rowbuf[2][8192];   // per row: [g2][T128][c32 swizzled]

    // zero-pad T in [0,8) and [104,128) for rows x g: 512 uint4, one/thread
    {
        const int row = tid >> 8, g = (tid >> 7) & 1, t = tid & 127;
        const int off = (t < 32) ? t * 8 : 3328 + (t - 32) * 8;
        *(uint4*)(&rowbuf[row][g * 4096 + off]) = make_uint4(0, 0, 0, 0);
    }

    const int wave = tid >> 6;
    const int lane = tid & 63;
    const int n    = lane & 15;   // u (B col) == A row within tile
    const int q    = lane >> 4;   // k-chunk / C row-group
    const ushortT* zb = zbuf + (size_t)b * 16384;

    // ---- Phase A (R5 form) ----
    {
        const int c = tid >> 3, colg = tid & 7, j0 = colg * 12;
        const int g_ = c >> 5, cl = c & 31, chunk = cl >> 3, pos = cl & 7;

        float w[9];
        #pragma unroll
        for (int i = 0; i < 9; ++i) w[i] = wx[c * 9 + i];
        const float bias = bx[c];
        const float* xb = x + (size_t)(b * 64 + c) * 9216;

        float acc0[12], acc1[12];
        #pragma unroll
        for (int jj = 0; jj < 12; ++jj) { acc0[jj] = bias; acc1[jj] = bias; }

        // input rows r0-1 .. r0+2, each loaded once (branchless, clamped)
        #pragma unroll
        for (int s = 0; s < 4; ++s) {
            const int rr  = r0 - 1 + s;
            const int rcl = (rr < 0) ? 0 : (rr > 95 ? 95 : rr);
            const bool rok = (rr >= 0) && (rr < 96);
            float f[20];
            #pragma unroll
            for (int m = 0; m < 5; ++m) {
                const int cs  = j0 - 4 + 4 * m;
                const int csc = (cs < 0) ? 0 : (cs > 92 ? 92 : cs);
                const float4 v = *(const float4*)(xb + rcl * 96 + csc);
                const bool ok = rok && (cs >= 0) && (cs <= 92);
                f[4 * m + 0] = ok ? v.x : 0.f;
                f[4 * m + 1] = ok ? v.y : 0.f;
                f[4 * m + 2] = ok ? v.z : 0.f;
                f[4 * m + 3] = ok ? v.w : 0.f;
            }
            if (s == 0) {
                #pragma unroll
                for (int jj = 0; jj < 12; ++jj)
                    acc0[jj] += f[jj+3]*w[0] + f[jj+4]*w[1] + f[jj+5]*w[2];
            } else if (s == 1) {
                #pragma unroll
                for (int jj = 0; jj < 12; ++jj) {
                    acc0[jj] += f[jj+3]*w[3] + f[jj+4]*w[4] + f[jj+5]*w[5]
                              + f[jj+4];                       // residual row r0
                    acc1[jj] += f[jj+3]*w[0] + f[jj+4]*w[1] + f[jj+5]*w[2];
                }
            } else if (s == 2) {
                #pragma unroll
                for (int jj = 0; jj < 12; ++jj) {
                    acc0[jj] += f[jj+3]*w[6] + f[jj+4]*w[7] + f[jj+5]*w[8];
                    acc1[jj] += f[jj+3]*w[3] + f[jj+4]*w[4] + f[jj+5]*w[5]
                              + f[jj+4];                       // residual row r0+1
                }
            } else {
                #pragma unroll
                for (int jj = 0; jj < 12; ++jj)
                    acc1[jj] += f[jj+3]*w[6] + f[jj+4]*w[7] + f[jj+5]*w[8];
            }
        }

        ushortT* rbw0 = &rowbuf[0][0] + g_ * 4096;
        ushortT* rbw1 = &rowbuf[1][0] + g_ * 4096;
        #pragma unroll
        for (int jj = 0; jj < 12; ++jj) {
            const int T  = j0 + jj + 8;
            const int sh = T * 32 + ((chunk ^ ((T >> 1) & 3)) << 3) + pos;
            rbw0[sh] = f2bf(gelu_fast(acc0[jj]));
            rbw1[sh] = f2bf(gelu_fast(acc1[jj]));
        }
    }

    // ---- NEW: preload g=0 B-fragments before the barrier (latency hidden
    // under the barrier's vmcnt drain; consumed only after __syncthreads) ----
    bf16x8 bfrag0[16];
    if (wave < 7) {
        #pragma unroll
        for (int v = 0; v < 16; ++v)
            bfrag0[v] = *(const bf16x8*)(zb + (v * 16 + n) * 64 + 8 * q);
    }
    __syncthreads();

    // ---- Phase B: MFMA, waves 0..6 own j-tile j0a = 16*wave ----
    if (wave < 7) {
        const int j0a = wave * 16;
        const ushortT* rb0 = &rowbuf[0][0];
        f32x4 acc0 = {0.f, 0.f, 0.f, 0.f};
        f32x4 acc1 = {0.f, 0.f, 0.f, 0.f};

        // issue g=1 B-fragment loads now; they fly under g=0's ds/MFMA work
        bf16x8 bfrag1[16];
        #pragma unroll
        for (int v = 0; v < 16; ++v)
            bfrag1[v] = *(const bf16x8*)(zb + (v * 16 + n) * 64 + 32 + 8 * q);

        // g = 0
        #pragma unroll
        for (int v = 0; v < 16; ++v) {
            const int T = j0a + n + v;
            const int off = T * 32 + ((q ^ ((T >> 1) & 3)) << 3);
            const bf16x8 a0 = *(const bf16x8*)(rb0 + off);
            acc0 = __builtin_amdgcn_mfma_f32_16x16x32_bf16(a0, bfrag0[v], acc0, 0, 0, 0);
            const bf16x8 a1 = *(const bf16x8*)(rb0 + 8192 + off);
            acc1 = __builtin_amdgcn_mfma_f32_16x16x32_bf16(a1, bfrag0[v], acc1, 0, 0, 0);
        }
        // g = 1 (A-side at +4096 elems = +8192 bytes within each row buffer)
        #pragma unroll
        for (int v = 0; v < 16; ++v) {
            const int T = j0a + n + v;
            const int off = (128 + T) * 32 + ((q ^ ((T >> 1) & 3)) << 3);
            const bf16x8 a0 = *(const bf16x8*)(rb0 + off);
            acc0 = __builtin_amdgcn_mfma_f32_16x16x32_bf16(a0, bfrag1[v], acc0, 0, 0, 0);
            const bf16x8 a1 = *(const bf16x8*)(rb0 + 8192 + off);
            acc1 = __builtin_amdgcn_mfma_f32_16x16x32_bf16(a1, bfrag1[v], acc1, 0, 0, 0);
        }

        // direct stores: part[b][r][ii=15-n][j0a+4q .. +3], disjoint per lane
        const int ii = 15 - n;
        const int joff = j0a + 4 * q;
        f32x4* p0 = (f32x4*)(part + ((size_t)(b * 96 + r0) * 16 + ii) * 112 + joff);
        *p0 = acc0;
        f32x4* p1 = (f32x4*)(part + ((size_t)(b * 96 + r0 + 1) * 16 + ii) * 112 + joff);
        *p1 = acc1;
    }
}

// ---------------------------------------------------------------------------
// K-reduce (vectorized): out[b][i][4j4..] = OUT_SCALE * sum_r part band rows.
// Each thread: 4 consecutive j via f32x4 band loads (<=16 terms).
// ---------------------------------------------------------------------------
__global__ __launch_bounds__(256) void k_reduce(
    const float* __restrict__ part, float* __restrict__ out)
{
    const int gid = blockIdx.x * 256 + threadIdx.x;
    if (gid >= 64 * 97 * 25) return;
    const int j4 = gid % 25;
    const int t  = gid / 25;
    const int i  = t % 97;
    const int b  = t / 97;
    const int j  = j4 * 4;

    int rlo = i - 8;  if (rlo < 0)  rlo = 0;
    int rhi = i + 7;  if (rhi > 95) rhi = 95;

    // index ((b*96 + r)*16 + (i-r+7))*112 + j ; per r++ delta = 15*112 = 1680
    const float* p = part + ((size_t)(b * 96 + rlo) * 16 + (i - rlo + 7)) * 112 + j;
    f32x4 s = {0.f, 0.f, 0.f, 0.f};
    for (int r = rlo; r <= rhi; ++r) {
        s += *(const f32x4*)p;
        p += 1680;
    }
    float* ob = out + (size_t)b * 9409 + i * 97 + j;
    ob[0] = s[0] * OUT_SCALE;
    if (j < 96) {
        ob[1] = s[1] * OUT_SCALE;
        ob[2] = s[2] * OUT_SCALE;
        ob[3] = s[3] * OUT_SCALE;
    }
}

// ---------------------------------------------------------------------------
extern "C" void kernel_launch(void* const* d_in, const int* in_sizes, int n_in,
                              void* d_out, int out_size, void* d_ws, size_t ws_size,
                              hipStream_t stream)
{
    const float* z  = (const float*)d_in[0];
    const float* x  = (const float*)d_in[1];
    const float* wz = (const float*)d_in[2];
    const float* bz = (const float*)d_in[3];
    const float* wx = (const float*)d_in[4];
    const float* bx = (const float*)d_in[5];
    float* out = (float*)d_out;

    // workspace: ZB (2 MB) then part[64][96][16][112] f32 (44.04 MB)
    ushortT* zbuf = (ushortT*)d_ws;
    float*   partw = (float*)((char*)d_ws + (size_t)64 * 16384 * 2);

    k_gelu_z<<<dim3(64, 4), 256, 0, stream>>>(z, wz, bz, zbuf);
    k_fused<<<dim3(3072), 512, 0, stream>>>(x, wx, bx, zbuf, partw);
    const int nred = 64 * 97 * 25;
    k_reduce<<<dim3((nred + 255) / 256), 256, 0, stream>>>(partw, out);

    (void)in_sizes; (void)n_in; (void)ws_size; (void)out_size;
}